// Round 1
// baseline (521.215 us; speedup 1.0000x reference)
//
#include <hip/hip_runtime.h>

// Problem constants (T,B,C,H,W) = (4,32,384,16,16), N = H*W = 256
#define T_ 4
#define B_ 32
#define C_ 384
#define N_ 256
#define HEADS_ 8
#define DH_ 48              // C_/HEADS_
#define BCN (B_*C_*N_)      // 3145728
#define EPS_ 1e-5f

// ---------------------------------------------------------------------------
// Kernel 1: LIF over the raw input x -> binary spikes s (u8)
// v_t = 0.5*v + x_t ; s = (v >= 1.0) ; hard reset v=0 on spike
// ---------------------------------------------------------------------------
__global__ __launch_bounds__(256)
void lif_input_kernel(const float* __restrict__ x, unsigned char* __restrict__ s)
{
    int i = blockIdx.x * 256 + threadIdx.x;
    if (i >= BCN) return;
    float v = 0.f;
#pragma unroll
    for (int t = 0; t < T_; ++t) {
        v = 0.5f * v + x[(size_t)t * BCN + i];
        unsigned char sp = (v >= 1.0f) ? 1 : 0;
        s[(size_t)t * BCN + i] = sp;
        if (sp) v = 0.f;
    }
}

// ---------------------------------------------------------------------------
// Kernel 2: fused (1x1 conv GEMM) + BN + LIF over time, per b.
// For fixed b, loops t=0..3 computing out[d,n] = sum_c W[d,c]*S[t,b,c,n],
// applies BN then the LIF recurrence (v in registers), writes spikes u8.
// Tile: 64(d) x 64(n), 256 threads, 4x4 microtile, BK=16.
// ---------------------------------------------------------------------------
__global__ __launch_bounds__(256)
void gemm_bn_lif_kernel(const float* __restrict__ W,
                        const unsigned char* __restrict__ S,
                        const float* __restrict__ gamma, const float* __restrict__ beta,
                        const float* __restrict__ mean,  const float* __restrict__ var,
                        unsigned char* __restrict__ spk)
{
    __shared__ float As[16][68];   // [k][d]  (+4 pad keeps 16B align, 2-way max)
    __shared__ float Bs[16][68];   // [k][n]

    const int tid = threadIdx.x;
    const int tx = tid & 15, ty = tid >> 4;
    const int n0 = blockIdx.x * 64;
    const int d0 = blockIdx.y * 64;
    const int b  = blockIdx.z;

    // BN constants for the 4 d-rows this thread owns
    float inv[4], add[4];
#pragma unroll
    for (int i = 0; i < 4; ++i) {
        int d = d0 + 4 * ty + i;
        float iv = gamma[d] / sqrtf(var[d] + EPS_);
        inv[i] = iv;
        add[i] = beta[d] - mean[d] * iv;
    }

    float v[4][4];
#pragma unroll
    for (int i = 0; i < 4; ++i)
#pragma unroll
        for (int j = 0; j < 4; ++j) v[i][j] = 0.f;

    const int ar = tid >> 2, ac = tid & 3;   // A staging: row, col-segment
    const int br = tid >> 4, bs = tid & 15;  // B staging: row, col-segment

    for (int t = 0; t < T_; ++t) {
        const unsigned char* St = S + (size_t)(t * B_ + b) * C_ * N_;
        float acc[4][4];
#pragma unroll
        for (int i = 0; i < 4; ++i)
#pragma unroll
            for (int j = 0; j < 4; ++j) acc[i][j] = 0.f;

        for (int kc = 0; kc < C_; kc += 16) {
            __syncthreads();
            // stage A: W[d0+ar][kc+4*ac .. +3]
            float4 av = *(const float4*)&W[(size_t)(d0 + ar) * C_ + kc + 4 * ac];
            As[4 * ac + 0][ar] = av.x;
            As[4 * ac + 1][ar] = av.y;
            As[4 * ac + 2][ar] = av.z;
            As[4 * ac + 3][ar] = av.w;
            // stage B: S[kc+br][n0+4*bs ..]  (u8 -> f32)
            uchar4 bv = *(const uchar4*)(St + (size_t)(kc + br) * N_ + n0 + 4 * bs);
            float4 bf = make_float4((float)bv.x, (float)bv.y, (float)bv.z, (float)bv.w);
            *(float4*)&Bs[br][4 * bs] = bf;
            __syncthreads();
#pragma unroll
            for (int kk = 0; kk < 16; ++kk) {
                float4 a4 = *(const float4*)&As[kk][4 * ty];
                float4 b4 = *(const float4*)&Bs[kk][4 * tx];
                float aa[4] = {a4.x, a4.y, a4.z, a4.w};
                float bb[4] = {b4.x, b4.y, b4.z, b4.w};
#pragma unroll
                for (int i = 0; i < 4; ++i)
#pragma unroll
                    for (int j = 0; j < 4; ++j)
                        acc[i][j] += aa[i] * bb[j];
            }
        }
        // epilogue: BN -> LIF -> spike store
        unsigned char* spt = spk + (size_t)(t * B_ + b) * C_ * N_;
#pragma unroll
        for (int i = 0; i < 4; ++i) {
            int d = d0 + 4 * ty + i;
#pragma unroll
            for (int j = 0; j < 4; ++j) {
                int n = n0 + 4 * tx + j;
                float bnv = acc[i][j] * inv[i] + add[i];
                float vv = 0.5f * v[i][j] + bnv;
                unsigned char sp = (vv >= 1.0f) ? 1 : 0;
                v[i][j] = sp ? 0.f : vv;
                spt[(size_t)d * N_ + n] = sp;
            }
        }
    }
}

// ---------------------------------------------------------------------------
// Kernel 3: per-head spike sums  Sq[t,b,h,n] = sum_{dh<48} q_spk[t,b,h*48+dh,n]
// ---------------------------------------------------------------------------
__global__ __launch_bounds__(256)
void head_sum_kernel(const unsigned char* __restrict__ q_spk, float* __restrict__ Sq)
{
    int i = blockIdx.x * 256 + threadIdx.x;       // T*B*Hh*N = 262144
    if (i >= T_ * B_ * HEADS_ * N_) return;
    int n = i & (N_ - 1);
    int rest = i >> 8;
    int h = rest & (HEADS_ - 1);
    int tb = rest >> 3;
    const unsigned char* p = q_spk + ((size_t)tb * C_ + h * DH_) * N_ + n;
    int ssum = 0;
#pragma unroll
    for (int dh = 0; dh < DH_; ++dh) ssum += p[(size_t)dh * N_];
    Sq[i] = (float)ssum;
}

// ---------------------------------------------------------------------------
// Kernel 4: decayed memory + attention LIF (threshold 0.5)
// M_0 = Sq_0 ; M_t = a*M_{t-1} + (1-a)*Sq_{t-1} ; qsum = M_t + Sq_t
// ---------------------------------------------------------------------------
__global__ __launch_bounds__(256)
void attn_kernel(const float* __restrict__ Sq, const float* __restrict__ alpha_p,
                 unsigned char* __restrict__ attn)
{
    int i = blockIdx.x * 256 + threadIdx.x;       // B*Hh*N = 65536
    if (i >= B_ * HEADS_ * N_) return;
    const float alpha = alpha_p[0];
    const int stride = B_ * HEADS_ * N_;
    float M = 0.f, v = 0.f, Sprev = 0.f;
#pragma unroll
    for (int t = 0; t < T_; ++t) {
        float Sqt = Sq[(size_t)t * stride + i];
        if (t == 0) M = Sqt;
        else        M = alpha * M + (1.f - alpha) * Sprev;
        float qsum = M + Sqt;
        float vv = 0.5f * v + qsum;
        unsigned char sp = (vv >= 0.5f) ? 1 : 0;
        v = sp ? 0.f : vv;
        attn[(size_t)t * stride + i] = sp;
        Sprev = Sqt;
    }
}

// ---------------------------------------------------------------------------
// Kernel 5: proj GEMM. B-operand built on the fly: (attn[h] & k_spk[c]) in {0,1}.
// Epilogue: (+bias) then BN, write fp32 to d_out.
// ---------------------------------------------------------------------------
__global__ __launch_bounds__(256)
void proj_gemm_kernel(const float* __restrict__ W,
                      const unsigned char* __restrict__ k_spk,
                      const unsigned char* __restrict__ attn,
                      const float* __restrict__ bias,
                      const float* __restrict__ gamma, const float* __restrict__ beta,
                      const float* __restrict__ mean,  const float* __restrict__ var,
                      float* __restrict__ out)
{
    __shared__ float As[16][68];
    __shared__ float Bs[16][68];

    const int tid = threadIdx.x;
    const int tx = tid & 15, ty = tid >> 4;
    const int n0 = blockIdx.x * 64;
    const int d0 = blockIdx.y * 64;
    const int tb = blockIdx.z;    // t*B + b

    float inv[4], add[4];
#pragma unroll
    for (int i = 0; i < 4; ++i) {
        int d = d0 + 4 * ty + i;
        float iv = gamma[d] / sqrtf(var[d] + EPS_);
        inv[i] = iv;
        add[i] = beta[d] - mean[d] * iv + bias[d] * iv;  // fold bias through BN
    }

    const unsigned char* Kt = k_spk + (size_t)tb * C_ * N_;
    const unsigned char* At = attn + (size_t)tb * HEADS_ * N_;

    const int ar = tid >> 2, ac = tid & 3;
    const int br = tid >> 4, bs = tid & 15;

    float acc[4][4];
#pragma unroll
    for (int i = 0; i < 4; ++i)
#pragma unroll
        for (int j = 0; j < 4; ++j) acc[i][j] = 0.f;

    for (int kc = 0; kc < C_; kc += 16) {
        __syncthreads();
        float4 av = *(const float4*)&W[(size_t)(d0 + ar) * C_ + kc + 4 * ac];
        As[4 * ac + 0][ar] = av.x;
        As[4 * ac + 1][ar] = av.y;
        As[4 * ac + 2][ar] = av.z;
        As[4 * ac + 3][ar] = av.w;
        int c = kc + br;
        int h = c / DH_;
        uchar4 kv = *(const uchar4*)(Kt + (size_t)c * N_ + n0 + 4 * bs);
        uchar4 avb = *(const uchar4*)(At + (size_t)h * N_ + n0 + 4 * bs);
        float4 bf = make_float4((float)(kv.x & avb.x), (float)(kv.y & avb.y),
                                (float)(kv.z & avb.z), (float)(kv.w & avb.w));
        *(float4*)&Bs[br][4 * bs] = bf;
        __syncthreads();
#pragma unroll
        for (int kk = 0; kk < 16; ++kk) {
            float4 a4 = *(const float4*)&As[kk][4 * ty];
            float4 b4 = *(const float4*)&Bs[kk][4 * tx];
            float aa[4] = {a4.x, a4.y, a4.z, a4.w};
            float bb[4] = {b4.x, b4.y, b4.z, b4.w};
#pragma unroll
            for (int i = 0; i < 4; ++i)
#pragma unroll
                for (int j = 0; j < 4; ++j)
                    acc[i][j] += aa[i] * bb[j];
        }
    }

    float* ot = out + (size_t)tb * C_ * N_;
#pragma unroll
    for (int i = 0; i < 4; ++i) {
        int d = d0 + 4 * ty + i;
#pragma unroll
        for (int j = 0; j < 4; ++j) {
            int n = n0 + 4 * tx + j;
            ot[(size_t)d * N_ + n] = acc[i][j] * inv[i] + add[i];
        }
    }
}

// ---------------------------------------------------------------------------
extern "C" void kernel_launch(void* const* d_in, const int* in_sizes, int n_in,
                              void* d_out, int out_size, void* d_ws, size_t ws_size,
                              hipStream_t stream)
{
    const float* x       = (const float*)d_in[0];
    const float* q_w     = (const float*)d_in[1];
    const float* q_gamma = (const float*)d_in[2];
    const float* q_beta  = (const float*)d_in[3];
    const float* q_mean  = (const float*)d_in[4];
    const float* q_var   = (const float*)d_in[5];
    const float* k_w     = (const float*)d_in[6];
    const float* k_gamma = (const float*)d_in[7];
    const float* k_beta  = (const float*)d_in[8];
    const float* k_mean  = (const float*)d_in[9];
    const float* k_var   = (const float*)d_in[10];
    const float* proj_w  = (const float*)d_in[11];
    const float* proj_b  = (const float*)d_in[12];
    const float* p_gamma = (const float*)d_in[13];
    const float* p_beta  = (const float*)d_in[14];
    const float* p_mean  = (const float*)d_in[15];
    const float* p_var   = (const float*)d_in[16];
    const float* m_alpha = (const float*)d_in[17];

    float* out = (float*)d_out;

    // workspace layout (u8 base)
    unsigned char* ws    = (unsigned char*)d_ws;
    unsigned char* s_u8  = ws;                                   // 12,582,912
    unsigned char* q_spk = ws + (size_t)1 * T_ * BCN;            // 12,582,912
    unsigned char* k_spk = ws + (size_t)2 * T_ * BCN;            // wait: BCN already excludes T
    // NOTE: T_*BCN would be wrong; sizes below are per full (T,B,C,N) tensor:
    // full spike tensor = T_*B_*C_*N_ = 12,582,912 bytes = 4*BCN? No: BCN = B*C*N.
    // Recompute cleanly:
    const size_t SPK = (size_t)T_ * B_ * C_ * N_;                // 12,582,912
    s_u8  = ws;
    q_spk = ws + SPK;
    k_spk = ws + 2 * SPK;
    float* Sq = (float*)(ws + 3 * SPK);                          // 262,144 floats
    unsigned char* attn = ws + 3 * SPK + (size_t)T_ * B_ * HEADS_ * N_ * 4;

    // 1. input LIF -> s
    lif_input_kernel<<<(BCN + 255) / 256, 256, 0, stream>>>(x, s_u8);

    // 2. q and k paths: GEMM + BN + LIF fused over time
    dim3 ggrid(N_ / 64, C_ / 64, B_);
    gemm_bn_lif_kernel<<<ggrid, 256, 0, stream>>>(q_w, s_u8, q_gamma, q_beta, q_mean, q_var, q_spk);
    gemm_bn_lif_kernel<<<ggrid, 256, 0, stream>>>(k_w, s_u8, k_gamma, k_beta, k_mean, k_var, k_spk);

    // 3. per-head sums of q spikes
    head_sum_kernel<<<(T_ * B_ * HEADS_ * N_ + 255) / 256, 256, 0, stream>>>(q_spk, Sq);

    // 4. decayed memory + attn LIF
    attn_kernel<<<(B_ * HEADS_ * N_ + 255) / 256, 256, 0, stream>>>(Sq, m_alpha, attn);

    // 5. proj GEMM (+bias, BN) -> out
    dim3 pgrid(N_ / 64, C_ / 64, T_ * B_);
    proj_gemm_kernel<<<pgrid, 256, 0, stream>>>(proj_w, k_spk, attn, proj_b,
                                                p_gamma, p_beta, p_mean, p_var, out);
}

// Round 2
// 243.658 us; speedup vs baseline: 2.1391x; 2.1391x over previous
//
#include <hip/hip_runtime.h>

#define T_ 4
#define B_ 32
#define C_ 384
#define N_ 256
#define HEADS_ 8
#define DH_ 48
#define EPS_ 1e-5f

typedef _Float16 f16;
typedef __attribute__((ext_vector_type(8))) _Float16 f16x8;
typedef __attribute__((ext_vector_type(16))) float f32x16;

#define PSCALE     4096.0f
#define PSCALE_INV (1.0f/4096.0f)

// ---------------------------------------------------------------------------
// Weight split: w = p0 + p1/4096 (+ ~2^-22 residual). p1 scaled so it stays
// in the f16 normal range (no denormal-flush risk in MFMA).
// ---------------------------------------------------------------------------
__global__ __launch_bounds__(256)
void wsplit_kernel(const float* __restrict__ qw, const float* __restrict__ kw,
                   const float* __restrict__ pw,
                   f16* __restrict__ q2, f16* __restrict__ k2, f16* __restrict__ p2)
{
    int i = blockIdx.x * 256 + threadIdx.x;
    if (i >= C_ * C_) return;
    const int NW = C_ * C_;
    {
        float w = qw[i]; f16 a = (f16)w; f16 b = (f16)((w - (float)a) * PSCALE);
        q2[i] = a; q2[NW + i] = b;
    }
    {
        float w = kw[i]; f16 a = (f16)w; f16 b = (f16)((w - (float)a) * PSCALE);
        k2[i] = a; k2[NW + i] = b;
    }
    {
        float w = pw[i]; f16 a = (f16)w; f16 b = (f16)((w - (float)a) * PSCALE);
        p2[i] = a; p2[NW + i] = b;
    }
}

// ---------------------------------------------------------------------------
// LIF on raw input, writing spikes TRANSPOSED: s[t][b][n][c] (f16 0/1).
// Block handles one (b, n-tile 64, c-tile 64); LDS transpose per t.
// ---------------------------------------------------------------------------
__global__ __launch_bounds__(256)
void lif_transpose_kernel(const float* __restrict__ x, f16* __restrict__ s)
{
    __shared__ f16 Ls[64][72];
    const int tid = threadIdx.x;
    const int n0 = blockIdx.x * 64;
    const int c0 = blockIdx.y * 64;
    const int b  = blockIdx.z;
    const int cl = tid >> 4;        // 0..15
    const int nl = (tid & 15) * 4;  // 0..60

    float v[4][4];
#pragma unroll
    for (int i = 0; i < 4; ++i)
#pragma unroll
        for (int j = 0; j < 4; ++j) v[i][j] = 0.f;

    for (int t = 0; t < T_; ++t) {
        const float* xt = x + (((size_t)t * B_ + b) * C_) * N_;
#pragma unroll
        for (int i = 0; i < 4; ++i) {
            int c = c0 + cl + 16 * i;
            float4 xv = *(const float4*)&xt[(size_t)c * N_ + n0 + nl];
            float xa[4] = {xv.x, xv.y, xv.z, xv.w};
#pragma unroll
            for (int j = 0; j < 4; ++j) {
                float vv = 0.5f * v[i][j] + xa[j];
                int sp = (vv >= 1.0f) ? 1 : 0;
                v[i][j] = sp ? 0.f : vv;
                Ls[nl + j][cl + 16 * i] = sp ? (f16)1.0f : (f16)0.0f;
            }
        }
        __syncthreads();
        {
            int r = tid >> 2, ch = (tid & 3) * 16;
            uint4 w0 = *(const uint4*)&Ls[r][ch];
            uint4 w1 = *(const uint4*)&Ls[r][ch + 8];
            f16* dst = s + (((size_t)t * B_ + b) * N_ + n0 + r) * (size_t)C_ + c0 + ch;
            *(uint4*)dst = w0;
            *(uint4*)(dst + 8) = w1;
        }
        __syncthreads();
    }
}

// ---------------------------------------------------------------------------
// q/k path: MFMA GEMM (2 f16 planes, dual accumulators) + BN + LIF over t.
// out^T[n][d] = sum_c S[n][c] * W[d][c].  A = S^T (m=n), B = W^T (col=d).
// Block: 64n x 64d, 4 waves of 32x32, t-loop inside (LIF v-state in regs).
// Spikes written transposed [t][b][n][d] f16.
// ---------------------------------------------------------------------------
__global__ __launch_bounds__(256)
void qk_gemm_kernel(const f16* __restrict__ Wp,   // [2][C][C]
                    const f16* __restrict__ S,    // [T][B][N][C]
                    const float* __restrict__ gamma, const float* __restrict__ beta,
                    const float* __restrict__ mean,  const float* __restrict__ var,
                    f16* __restrict__ spk)        // [T][B][N][C]
{
    __shared__ f16 As[64][72];
    __shared__ f16 Bs[2][64][72];

    const int tid  = threadIdx.x;
    const int lane = tid & 63;
    const int wave = tid >> 6;
    const int wn = wave & 1, wd = wave >> 1;
    const int n0 = blockIdx.x * 64;
    const int d0 = blockIdx.y * 64;
    const int b  = blockIdx.z;

    const int l31 = lane & 31;
    const int lhi = lane >> 5;
    const int dcol = d0 + wd * 32 + l31;

    const float inv = gamma[dcol] / sqrtf(var[dcol] + EPS_);
    const float add = beta[dcol] - mean[dcol] * inv;

    const int sr = tid >> 2;
    const int sc = (tid & 3) * 16;

    float v[16];
#pragma unroll
    for (int r = 0; r < 16; ++r) v[r] = 0.f;

    for (int t = 0; t < T_; ++t) {
        const f16* St = S + (((size_t)t * B_ + b) * N_) * (size_t)C_;
        f32x16 acc0, acc1;
#pragma unroll
        for (int r = 0; r < 16; ++r) { acc0[r] = 0.f; acc1[r] = 0.f; }

        for (int kc = 0; kc < C_; kc += 64) {
            __syncthreads();
            const f16* ga = St + (size_t)(n0 + sr) * C_ + kc + sc;
            *(uint4*)&As[sr][sc]     = *(const uint4*)ga;
            *(uint4*)&As[sr][sc + 8] = *(const uint4*)(ga + 8);
            const f16* gb0 = Wp + (size_t)(d0 + sr) * C_ + kc + sc;
            *(uint4*)&Bs[0][sr][sc]     = *(const uint4*)gb0;
            *(uint4*)&Bs[0][sr][sc + 8] = *(const uint4*)(gb0 + 8);
            const f16* gb1 = gb0 + (size_t)C_ * C_;
            *(uint4*)&Bs[1][sr][sc]     = *(const uint4*)gb1;
            *(uint4*)&Bs[1][sr][sc + 8] = *(const uint4*)(gb1 + 8);
            __syncthreads();
#pragma unroll
            for (int kk = 0; kk < 4; ++kk) {
                const int ko = kk * 16 + lhi * 8;
                f16x8 af = *(const f16x8*)&As[wn * 32 + l31][ko];
                f16x8 b0 = *(const f16x8*)&Bs[0][wd * 32 + l31][ko];
                f16x8 b1 = *(const f16x8*)&Bs[1][wd * 32 + l31][ko];
                acc0 = __builtin_amdgcn_mfma_f32_32x32x16_f16(af, b0, acc0, 0, 0, 0);
                acc1 = __builtin_amdgcn_mfma_f32_32x32x16_f16(af, b1, acc1, 0, 0, 0);
            }
        }
        // epilogue: combine planes -> BN -> LIF -> spike store (transposed)
        f16* spt = spk + (((size_t)t * B_ + b) * N_) * (size_t)C_;
#pragma unroll
        for (int r = 0; r < 16; ++r) {
            int nrow = n0 + wn * 32 + (r & 3) + 8 * (r >> 2) + 4 * lhi;
            float val = acc0[r] + acc1[r] * PSCALE_INV;
            float bnv = val * inv + add;
            float vv = 0.5f * v[r] + bnv;
            int sp = (vv >= 1.0f) ? 1 : 0;
            v[r] = sp ? 0.f : vv;
            spt[(size_t)nrow * C_ + dcol] = sp ? (f16)1.0f : (f16)0.0f;
        }
    }
}

// ---------------------------------------------------------------------------
// Per-head spike counts from q spikes (transposed layout): Sq[t][b][h][n]
// f16 1.0 = 0x3C00 -> count via popcount of bit 10 per halfword.
// ---------------------------------------------------------------------------
__global__ __launch_bounds__(256)
void head_sum_kernel(const f16* __restrict__ q_spk, float* __restrict__ Sq)
{
    int i = blockIdx.x * 256 + threadIdx.x;
    if (i >= T_ * B_ * HEADS_ * N_) return;
    int n  = i & (N_ - 1);
    int h  = (i >> 8) & (HEADS_ - 1);
    int tb = i >> 11;
    const uint4* p = (const uint4*)(q_spk + ((size_t)tb * N_ + n) * C_ + h * DH_);
    int cnt = 0;
#pragma unroll
    for (int j = 0; j < 6; ++j) {
        uint4 w = p[j];
        cnt += __popc(w.x & 0x04000400u) + __popc(w.y & 0x04000400u)
             + __popc(w.z & 0x04000400u) + __popc(w.w & 0x04000400u);
    }
    Sq[i] = (float)cnt;
}

// ---------------------------------------------------------------------------
// Decayed memory + attention LIF (threshold 0.5) -> attn u8 [t][b][h][n]
// ---------------------------------------------------------------------------
__global__ __launch_bounds__(256)
void attn_kernel(const float* __restrict__ Sq, const float* __restrict__ alpha_p,
                 unsigned char* __restrict__ attn)
{
    int i = blockIdx.x * 256 + threadIdx.x;
    if (i >= B_ * HEADS_ * N_) return;
    const float alpha = alpha_p[0];
    const int stride = B_ * HEADS_ * N_;
    float M = 0.f, v = 0.f, Sprev = 0.f;
#pragma unroll
    for (int t = 0; t < T_; ++t) {
        float Sqt = Sq[(size_t)t * stride + i];
        if (t == 0) M = Sqt;
        else        M = alpha * M + (1.f - alpha) * Sprev;
        float qsum = M + Sqt;
        float vv = 0.5f * v + qsum;
        unsigned char sp = (vv >= 0.5f) ? 1 : 0;
        v = sp ? 0.f : vv;
        attn[(size_t)t * stride + i] = sp;
        Sprev = Sqt;
    }
}

// ---------------------------------------------------------------------------
// proj GEMM: A = (attn & k_spk)[n][c] built during staging; 2 f16 planes;
// epilogue bias+BN -> fp32 out [t][b][d][n]. Grid z = t*B+b (no recurrence).
// ---------------------------------------------------------------------------
__global__ __launch_bounds__(256)
void proj_gemm_kernel(const f16* __restrict__ Wp,   // [2][C][C]
                      const f16* __restrict__ K,    // [T][B][N][C]
                      const unsigned char* __restrict__ attn, // [T][B][H][N]
                      const float* __restrict__ bias,
                      const float* __restrict__ gamma, const float* __restrict__ beta,
                      const float* __restrict__ mean,  const float* __restrict__ var,
                      float* __restrict__ out)      // [T][B][C][N]
{
    __shared__ f16 As[64][72];
    __shared__ f16 Bs[2][64][72];

    const int tid  = threadIdx.x;
    const int lane = tid & 63;
    const int wave = tid >> 6;
    const int wn = wave & 1, wd = wave >> 1;
    const int n0 = blockIdx.x * 64;
    const int d0 = blockIdx.y * 64;
    const int tb = blockIdx.z;

    const int l31 = lane & 31;
    const int lhi = lane >> 5;
    const int dcol = d0 + wd * 32 + l31;

    const float inv = gamma[dcol] / sqrtf(var[dcol] + EPS_);
    const float add = beta[dcol] - mean[dcol] * inv + bias[dcol] * inv;

    const int sr = tid >> 2;
    const int sc = (tid & 3) * 16;

    const f16* Kt = K + (size_t)tb * N_ * C_;
    const unsigned char* At = attn + (size_t)tb * HEADS_ * N_;

    f32x16 acc0, acc1;
#pragma unroll
    for (int r = 0; r < 16; ++r) { acc0[r] = 0.f; acc1[r] = 0.f; }

    for (int kc = 0; kc < C_; kc += 64) {
        __syncthreads();
        // A: attn-masked k spikes. chunk [c, c+15] stays within one head (16|48)
        {
            int c = kc + sc;
            int h = c / DH_;
            unsigned char am = At[(size_t)h * N_ + n0 + sr];
            if (am) {
                const f16* ga = Kt + (size_t)(n0 + sr) * C_ + c;
                *(uint4*)&As[sr][sc]     = *(const uint4*)ga;
                *(uint4*)&As[sr][sc + 8] = *(const uint4*)(ga + 8);
            } else {
                uint4 z = make_uint4(0, 0, 0, 0);
                *(uint4*)&As[sr][sc]     = z;
                *(uint4*)&As[sr][sc + 8] = z;
            }
        }
        const f16* gb0 = Wp + (size_t)(d0 + sr) * C_ + kc + sc;
        *(uint4*)&Bs[0][sr][sc]     = *(const uint4*)gb0;
        *(uint4*)&Bs[0][sr][sc + 8] = *(const uint4*)(gb0 + 8);
        const f16* gb1 = gb0 + (size_t)C_ * C_;
        *(uint4*)&Bs[1][sr][sc]     = *(const uint4*)gb1;
        *(uint4*)&Bs[1][sr][sc + 8] = *(const uint4*)(gb1 + 8);
        __syncthreads();
#pragma unroll
        for (int kk = 0; kk < 4; ++kk) {
            const int ko = kk * 16 + lhi * 8;
            f16x8 af = *(const f16x8*)&As[wn * 32 + l31][ko];
            f16x8 b0 = *(const f16x8*)&Bs[0][wd * 32 + l31][ko];
            f16x8 b1 = *(const f16x8*)&Bs[1][wd * 32 + l31][ko];
            acc0 = __builtin_amdgcn_mfma_f32_32x32x16_f16(af, b0, acc0, 0, 0, 0);
            acc1 = __builtin_amdgcn_mfma_f32_32x32x16_f16(af, b1, acc1, 0, 0, 0);
        }
    }
    // epilogue: lane owns fixed d, n varies by reg -> 4x float4 stores
    float* orow = out + ((size_t)tb * C_ + dcol) * N_ + n0 + wn * 32 + 4 * lhi;
#pragma unroll
    for (int g = 0; g < 4; ++g) {
        float4 o;
        float v0 = acc0[g * 4 + 0] + acc1[g * 4 + 0] * PSCALE_INV;
        float v1 = acc0[g * 4 + 1] + acc1[g * 4 + 1] * PSCALE_INV;
        float v2 = acc0[g * 4 + 2] + acc1[g * 4 + 2] * PSCALE_INV;
        float v3 = acc0[g * 4 + 3] + acc1[g * 4 + 3] * PSCALE_INV;
        o.x = v0 * inv + add;
        o.y = v1 * inv + add;
        o.z = v2 * inv + add;
        o.w = v3 * inv + add;
        *(float4*)&orow[8 * g] = o;
    }
}

// ---------------------------------------------------------------------------
extern "C" void kernel_launch(void* const* d_in, const int* in_sizes, int n_in,
                              void* d_out, int out_size, void* d_ws, size_t ws_size,
                              hipStream_t stream)
{
    const float* x       = (const float*)d_in[0];
    const float* q_w     = (const float*)d_in[1];
    const float* q_gamma = (const float*)d_in[2];
    const float* q_beta  = (const float*)d_in[3];
    const float* q_mean  = (const float*)d_in[4];
    const float* q_var   = (const float*)d_in[5];
    const float* k_w     = (const float*)d_in[6];
    const float* k_gamma = (const float*)d_in[7];
    const float* k_beta  = (const float*)d_in[8];
    const float* k_mean  = (const float*)d_in[9];
    const float* k_var   = (const float*)d_in[10];
    const float* proj_w  = (const float*)d_in[11];
    const float* proj_b  = (const float*)d_in[12];
    const float* p_gamma = (const float*)d_in[13];
    const float* p_beta  = (const float*)d_in[14];
    const float* p_mean  = (const float*)d_in[15];
    const float* p_var   = (const float*)d_in[16];
    const float* m_alpha = (const float*)d_in[17];

    float* out = (float*)d_out;

    const size_t SPK_BYTES = (size_t)T_ * B_ * N_ * C_ * sizeof(f16); // 25,165,824
    const size_t W2_BYTES  = (size_t)2 * C_ * C_ * sizeof(f16);       // 589,824
    const size_t SQ_BYTES  = (size_t)T_ * B_ * HEADS_ * N_ * sizeof(float);

    unsigned char* ws = (unsigned char*)d_ws;
    size_t off = 0;
    auto carve = [&](size_t bytes) {
        off = (off + 255) & ~(size_t)255;
        void* p = ws + off;
        off += bytes;
        return p;
    };
    f16* s_f16  = (f16*)carve(SPK_BYTES);
    f16* q_spk  = (f16*)carve(SPK_BYTES);
    f16* k_spk  = (f16*)carve(SPK_BYTES);
    f16* Wq2    = (f16*)carve(W2_BYTES);
    f16* Wk2    = (f16*)carve(W2_BYTES);
    f16* Wp2    = (f16*)carve(W2_BYTES);
    float* Sq   = (float*)carve(SQ_BYTES);
    unsigned char* attn = (unsigned char*)carve((size_t)T_ * B_ * HEADS_ * N_);

    // 1. weight splits (f16 plane pairs)
    wsplit_kernel<<<(C_ * C_ + 255) / 256, 256, 0, stream>>>(q_w, k_w, proj_w, Wq2, Wk2, Wp2);

    // 2. input LIF + transpose -> s_f16 [t][b][n][c]
    dim3 lgrid(N_ / 64, C_ / 64, B_);
    lif_transpose_kernel<<<lgrid, 256, 0, stream>>>(x, s_f16);

    // 3. q and k paths (MFMA GEMM + BN + LIF)
    dim3 ggrid(N_ / 64, C_ / 64, B_);
    qk_gemm_kernel<<<ggrid, 256, 0, stream>>>(Wq2, s_f16, q_gamma, q_beta, q_mean, q_var, q_spk);
    qk_gemm_kernel<<<ggrid, 256, 0, stream>>>(Wk2, s_f16, k_gamma, k_beta, k_mean, k_var, k_spk);

    // 4. per-head q spike counts
    head_sum_kernel<<<(T_ * B_ * HEADS_ * N_ + 255) / 256, 256, 0, stream>>>(q_spk, Sq);

    // 5. decayed memory + attn LIF
    attn_kernel<<<(B_ * HEADS_ * N_ + 255) / 256, 256, 0, stream>>>(Sq, m_alpha, attn);

    // 6. proj GEMM -> out
    dim3 pgrid(N_ / 64, C_ / 64, T_ * B_);
    proj_gemm_kernel<<<pgrid, 256, 0, stream>>>(Wp2, k_spk, attn, proj_b,
                                                p_gamma, p_beta, p_mean, p_var, out);
}